// Round 4
// baseline (436.985 us; speedup 1.0000x reference)
//
#include <hip/hip_runtime.h>

#define NN 8192
#define HH 64
constexpr float LALPHA = 0.2f;

typedef __attribute__((ext_vector_type(8))) short bf16x8;
typedef __attribute__((ext_vector_type(4))) float f32x4;

__device__ inline short f2bf(float f) {
  unsigned u = __builtin_bit_cast(unsigned, f);
  u += 0x7FFFu + ((u >> 16) & 1u);
  return (short)(u >> 16);
}

// inline-asm global loads: compiler inserts NO waitcnt for these; we own it.
#define GLD(dst, p, offstr) \
  asm volatile("global_load_dwordx4 %0, %1, off offset:" offstr : "=v"(dst) : "v"(p))
#define WAITVM(nstr)                                    \
  do {                                                  \
    asm volatile("s_waitcnt vmcnt(" nstr ")" ::: "memory"); \
    __builtin_amdgcn_sched_barrier(0);                  \
  } while (0)

// ---------------------------------------------------------------- diag extract
__global__ __launch_bounds__(256) void k_diag(const float* __restrict__ na,
                                              const float* __restrict__ ea,
                                              float* __restrict__ dn,
                                              float* __restrict__ de) {
  int i = blockIdx.x * 256 + threadIdx.x;
  if (i < NN) {
    dn[i] = na[(size_t)i * NN + i];
    de[i] = ea[(size_t)i * NN + i];
  }
}

// ---------------------------------------------------------------- column sums of h
__global__ __launch_bounds__(256) void k_hbarP(const float* __restrict__ h,
                                               float* __restrict__ HbP) {
  int c = threadIdx.x & 63, rs = threadIdx.x >> 6;
  int r0 = blockIdx.x * 128;
  float s = 0.f;
  for (int r = rs; r < 128; r += 4) s += h[(size_t)(r0 + r) * HH + c];
  __shared__ float red[4][64];
  red[rs][c] = s;
  __syncthreads();
  if (rs == 0) HbP[blockIdx.x * 64 + c] = red[0][c] + red[1][c] + red[2][c] + red[3][c];
}

__global__ __launch_bounds__(64) void k_hbarF(const float* __restrict__ HbP,
                                              float* __restrict__ Hb) {
  int c = threadIdx.x;
  float s = 0.f;
  for (int b = 0; b < 64; ++b) s += HbP[b * 64 + c];
  Hb[c] = s;
}

// ---------------------------------------------------------------- h -> ht (transposed bf16 [64][NN])
__global__ __launch_bounds__(256) void k_ht(const float* __restrict__ h,
                                            unsigned short* __restrict__ ht) {
  __shared__ float tile[64][65];
  int j0 = blockIdx.x * 64;
  for (int l = threadIdx.x; l < 64 * 64; l += 256) {
    int r = l >> 6, c = l & 63;
    tile[r][c] = h[(size_t)(j0 + r) * HH + c];
  }
  __syncthreads();
  for (int l = threadIdx.x; l < 64 * 64; l += 256) {
    int c = l >> 6, r = l & 63;
    ht[(size_t)c * NN + j0 + r] = (unsigned short)f2bf(tile[r][c]);
  }
}

// ---------------------------------------------------------------- heavy masked matmuls via MFMA
// Sp_raw = (na>0)@h, Tf_raw = ea@h, Tp_raw = relu(ea)@h, cp_raw = #(ea>0) per row
// FIFO-ordered pipeline: per iter issue [ht(c)] then [adj(c+1)], wait vmcnt(4)
// -> adj(c)+ht(c) ready, adj(c+1) stays in flight across compute.
template <int KS>
__global__ __launch_bounds__(256, 4) void k_stageA(
    const float* __restrict__ na, const float* __restrict__ ea,
    const unsigned short* __restrict__ ht,
    float* __restrict__ SpP, float* __restrict__ TfP,
    float* __restrict__ TpP, float* __restrict__ cpP) {
  const int lane  = threadIdx.x & 63;
  const int wid   = threadIdx.x >> 6;
  const int row16 = lane & 15;
  const int kgrp  = lane >> 4;
  const int i0    = blockIdx.x * 64 + wid * 16;
  const int ks    = blockIdx.y;
  const int kbeg  = ks * (NN / KS);
  constexpr int ITERS = NN / KS / 32;  // 32 (KS=8) or 64 (KS=4); even

  f32x4 accS[4] = {}, accF[4] = {}, accP[4] = {};
  float cnt = 0.f;

  const float* naP = na + (size_t)(i0 + row16) * NN + kbeg + kgrp * 8;
  const float* eaP = ea + (size_t)(i0 + row16) * NN + kbeg + kgrp * 8;
  const unsigned short* htP0 = ht + (size_t)row16 * NN + kbeg + kgrp * 8;
  const unsigned short* htP1 = htP0 + (size_t)16 * NN;
  const unsigned short* htP2 = htP0 + (size_t)32 * NN;
  const unsigned short* htP3 = htP0 + (size_t)48 * NN;

  f32x4 Aa0, Aa1, Ea0, Ea1, Ab0, Ab1, Eb0, Eb1;
  bf16x8 Bv0, Bv1, Bv2, Bv3;

#define HTLOAD(offstr)        \
  GLD(Bv0, htP0, offstr);     \
  GLD(Bv1, htP1, offstr);     \
  GLD(Bv2, htP2, offstr);     \
  GLD(Bv3, htP3, offstr)

#define COMPUTE(A0, A1, E0, E1)                                              \
  do {                                                                       \
    const float av[8] = {A0[0], A0[1], A0[2], A0[3], A1[0], A1[1], A1[2], A1[3]}; \
    const float ev[8] = {E0[0], E0[1], E0[2], E0[3], E1[0], E1[1], E1[2], E1[3]}; \
    bf16x8 fS, fF, fP;                                                       \
    _Pragma("unroll") for (int q = 0; q < 8; ++q) {                          \
      fS[q] = (av[q] > 0.f) ? (short)0x3F80 : (short)0;                      \
      fF[q] = f2bf(ev[q]);                                                   \
      fP[q] = f2bf(fmaxf(ev[q], 0.f));                                       \
      cnt += (ev[q] > 0.f) ? 1.f : 0.f;                                      \
    }                                                                        \
    accS[0] = __builtin_amdgcn_mfma_f32_16x16x32_bf16(fS, Bv0, accS[0], 0, 0, 0); \
    accF[0] = __builtin_amdgcn_mfma_f32_16x16x32_bf16(fF, Bv0, accF[0], 0, 0, 0); \
    accP[0] = __builtin_amdgcn_mfma_f32_16x16x32_bf16(fP, Bv0, accP[0], 0, 0, 0); \
    accS[1] = __builtin_amdgcn_mfma_f32_16x16x32_bf16(fS, Bv1, accS[1], 0, 0, 0); \
    accF[1] = __builtin_amdgcn_mfma_f32_16x16x32_bf16(fF, Bv1, accF[1], 0, 0, 0); \
    accP[1] = __builtin_amdgcn_mfma_f32_16x16x32_bf16(fP, Bv1, accP[1], 0, 0, 0); \
    accS[2] = __builtin_amdgcn_mfma_f32_16x16x32_bf16(fS, Bv2, accS[2], 0, 0, 0); \
    accF[2] = __builtin_amdgcn_mfma_f32_16x16x32_bf16(fF, Bv2, accF[2], 0, 0, 0); \
    accP[2] = __builtin_amdgcn_mfma_f32_16x16x32_bf16(fP, Bv2, accP[2], 0, 0, 0); \
    accS[3] = __builtin_amdgcn_mfma_f32_16x16x32_bf16(fS, Bv3, accS[3], 0, 0, 0); \
    accF[3] = __builtin_amdgcn_mfma_f32_16x16x32_bf16(fF, Bv3, accF[3], 0, 0, 0); \
    accP[3] = __builtin_amdgcn_mfma_f32_16x16x32_bf16(fP, Bv3, accP[3], 0, 0, 0); \
  } while (0)

  // prologue: adj(iter0) -> a-set (oldest in FIFO)
  GLD(Aa0, naP, "0");
  GLD(Aa1, naP, "16");
  GLD(Ea0, eaP, "0");
  GLD(Ea1, eaP, "16");

  for (int t = 0; t < (ITERS - 2) / 2; ++t) {
    // even iter: consume a, prefetch b @+128B
    HTLOAD("0");
    GLD(Ab0, naP, "128");
    GLD(Ab1, naP, "144");
    GLD(Eb0, eaP, "128");
    GLD(Eb1, eaP, "144");
    WAITVM("4");
    COMPUTE(Aa0, Aa1, Ea0, Ea1);
    // odd iter: consume b, prefetch a @+256B
    HTLOAD("64");
    GLD(Aa0, naP, "256");
    GLD(Aa1, naP, "272");
    GLD(Ea0, eaP, "256");
    GLD(Ea1, eaP, "272");
    WAITVM("4");
    COMPUTE(Ab0, Ab1, Eb0, Eb1);
    naP += 64; eaP += 64;
    htP0 += 64; htP1 += 64; htP2 += 64; htP3 += 64;
  }
  // tail (last 2 iters): even-tail prefetches b, odd-tail drains
  HTLOAD("0");
  GLD(Ab0, naP, "128");
  GLD(Ab1, naP, "144");
  GLD(Eb0, eaP, "128");
  GLD(Eb1, eaP, "144");
  WAITVM("4");
  COMPUTE(Aa0, Aa1, Ea0, Ea1);
  HTLOAD("64");
  WAITVM("0");
  COMPUTE(Ab0, Ab1, Eb0, Eb1);

#undef HTLOAD
#undef COMPUTE

  cnt += __shfl_xor(cnt, 16);
  cnt += __shfl_xor(cnt, 32);
  if (lane < 16) cpP[ks * NN + i0 + lane] = cnt;

  const size_t base = (size_t)ks * ((size_t)NN * HH);
#pragma unroll
  for (int c = 0; c < 4; ++c) {
#pragma unroll
    for (int r = 0; r < 4; ++r) {
      const int row = i0 + kgrp * 4 + r;
      const int col = c * 16 + row16;
      const size_t idx = base + (size_t)row * HH + col;
      SpP[idx] = accS[c][r];
      TfP[idx] = accF[c][r];
      TpP[idx] = accP[c][r];
    }
  }
}

// ---------------------------------------------------------------- combine partials
template <int KS>
__global__ __launch_bounds__(256) void k_combine(
    const float* __restrict__ h, const float* __restrict__ dn,
    const float* __restrict__ de, const float* __restrict__ Hb,
    float* __restrict__ SpP, float* __restrict__ TfP,
    float* __restrict__ TpP, const float* __restrict__ cpP,
    float* __restrict__ cpF) {
  const int SZ = NN * HH;
  int idx = blockIdx.x * 256 + threadIdx.x;
  int i = idx >> 6, c = idx & 63;
  float hic = h[idx];
  float dni = dn[i], dei = de[i];
  float sp = 0.f, tf = 0.f, tp = 0.f;
#pragma unroll
  for (int s = 0; s < KS; ++s) {
    sp += SpP[(size_t)s * SZ + idx];
    tf += TfP[(size_t)s * SZ + idx];
    tp += TpP[(size_t)s * SZ + idx];
  }
  sp -= (dni > 0.f) ? hic : 0.f;
  tf -= dei * hic;
  tp -= fmaxf(dei, 0.f) * hic;
  SpP[idx] = sp;                       // Sp
  SpP[SZ + idx] = Hb[c] - hic - sp;    // Sm
  TpP[idx] = tp;                       // Tp
  TpP[SZ + idx] = tf - tp;             // Tm
  if (idx < NN) {
    float cntv = 0.f;
#pragma unroll
    for (int s = 0; s < KS; ++s) cntv += cpP[s * NN + idx];
    cntv -= (de[idx] > 0.f) ? 1.f : 0.f;
    cpF[idx] = cntv;
  }
}

// ---------------------------------------------------------------- [N,64] @ [64,64]
__global__ __launch_bounds__(256) void k_mm64(const float* __restrict__ X,
                                              const float* __restrict__ W,
                                              float* __restrict__ Y) {
  __shared__ float Ws[64][64];
  __shared__ float Xs[16][64];
  const int t = threadIdx.x;
  for (int l = t; l < 4096; l += 256) Ws[l >> 6][l & 63] = W[l];
  const int i0 = blockIdx.x * 16;
  for (int l = t; l < 1024; l += 256)
    Xs[l >> 6][l & 63] = X[(size_t)(i0 + (l >> 6)) * 64 + (l & 63)];
  __syncthreads();
  const int lane = t & 63, wid = t >> 6;
  float acc[4] = {0.f, 0.f, 0.f, 0.f};
  for (int k = 0; k < 64; ++k) {
    float wv = Ws[k][lane];
#pragma unroll
    for (int r = 0; r < 4; ++r) acc[r] += Xs[wid * 4 + r][k] * wv;
  }
#pragma unroll
  for (int r = 0; r < 4; ++r) Y[(size_t)(i0 + wid * 4 + r) * 64 + lane] = acc[r];
}

// ---------------------------------------------------------------- analytic GAT softmax
__global__ __launch_bounds__(256) void k_gat(
    const float* __restrict__ HP, const float* __restrict__ HM,
    const float* __restrict__ a, const float* __restrict__ Tp,
    const float* __restrict__ Tm, const float* __restrict__ cpF,
    float* __restrict__ U) {
  const int lane = threadIdx.x & 63;
  const int i = blockIdx.x * 4 + (threadIdx.x >> 6);
  const int idx = i * 64 + lane;
  float hp = HP[idx], hm = HM[idx];
  float a0 = a[lane], a1 = a[64 + lane];
  float ep = hp * a0 + hm * a1;
  float em = hm * a0 + hp * a1;
#pragma unroll
  for (int off = 32; off >= 1; off >>= 1) {
    ep += __shfl_xor(ep, off);
    em += __shfl_xor(em, off);
  }
  ep = ep > 0.f ? ep : LALPHA * ep;
  em = em > 0.f ? em : LALPHA * em;
  float cp = cpF[i];
  float cm = (float)(NN - 1) - cp;
  const float NEGI = -3.0e38f;
  float m = fmaxf(cp > 0.f ? ep : NEGI, cm > 0.f ? em : NEGI);
  float xp = (cp > 0.f) ? expf(ep - m) : 0.f;
  float xm = (cm > 0.f) ? expf(em - m) : 0.f;
  float denom = cp * xp + cm * xm;
  float inv = denom > 0.f ? 1.f / denom : 0.f;
  float wp = xp * inv, wm = xm * inv;
  U[idx] = wp * Tp[idx] + wm * Tm[idx];
}

// ---------------------------------------------------------------- GRU cell (r,z,n)
template <int XK>
__global__ __launch_bounds__(64) void k_gru(
    const float* __restrict__ x1, const float* __restrict__ x2,
    const float* __restrict__ wih, const float* __restrict__ whh,
    const float* __restrict__ bih, const float* __restrict__ bhh,
    const float* __restrict__ h, float* __restrict__ out) {
  const int c = threadIdx.x;
  const int i0 = blockIdx.x * 8;
  __shared__ float xs[8][XK];
  __shared__ float hs[8][64];
  for (int l = c; l < 8 * XK; l += 64) {
    int r = l / XK, k = l % XK;
    float v;
    if (XK == 128)
      v = (k < 64) ? x1[(size_t)(i0 + r) * 64 + k]
                   : x2[(size_t)(i0 + r) * 64 + (k - 64)];
    else
      v = x1[(size_t)(i0 + r) * 64 + k];
    xs[r][k] = v;
  }
  for (int l = c; l < 8 * 64; l += 64) {
    int r = l >> 6, k = l & 63;
    hs[r][k] = h[(size_t)(i0 + r) * 64 + k];
  }
  __syncthreads();
  float gr[8] = {}, gz[8] = {}, gn[8] = {};
  for (int k = 0; k < XK; ++k) {
    float wr = wih[(size_t)c * XK + k];
    float wz = wih[(size_t)(64 + c) * XK + k];
    float wn = wih[(size_t)(128 + c) * XK + k];
#pragma unroll
    for (int r = 0; r < 8; ++r) {
      float xv = xs[r][k];
      gr[r] += xv * wr; gz[r] += xv * wz; gn[r] += xv * wn;
    }
  }
  float hr[8] = {}, hz[8] = {}, hn[8] = {};
  for (int k = 0; k < 64; ++k) {
    float ur = whh[(size_t)c * 64 + k];
    float uz = whh[(size_t)(64 + c) * 64 + k];
    float un = whh[(size_t)(128 + c) * 64 + k];
#pragma unroll
    for (int r = 0; r < 8; ++r) {
      float hv = hs[r][k];
      hr[r] += hv * ur; hz[r] += hv * uz; hn[r] += hv * un;
    }
  }
  float br = bih[c], bz = bih[64 + c], bn = bih[128 + c];
  float dr = bhh[c], dz = bhh[64 + c], dnb = bhh[128 + c];
#pragma unroll
  for (int r = 0; r < 8; ++r) {
    float rg = 1.f / (1.f + expf(-(gr[r] + br + hr[r] + dr)));
    float zg = 1.f / (1.f + expf(-(gz[r] + bz + hz[r] + dz)));
    float ng = tanhf(gn[r] + bn + rg * (hn[r] + dnb));
    out[(size_t)(i0 + r) * 64 + c] = (1.f - zg) * ng + zg * hs[r][c];
  }
}

// ---------------------------------------------------------------- final combine
__global__ __launch_bounds__(256) void k_final(const float* __restrict__ dn,
                                               const float* __restrict__ de,
                                               const float* __restrict__ EO,
                                               const float* __restrict__ NO,
                                               float* __restrict__ out) {
  int idx = blockIdx.x * 256 + threadIdx.x;
  int i = idx >> 6;
  out[idx] = de[i] * EO[idx] + dn[i] * NO[idx];
}

extern "C" void kernel_launch(void* const* d_in, const int* in_sizes, int n_in,
                              void* d_out, int out_size, void* d_ws, size_t ws_size,
                              hipStream_t stream) {
  const float* h    = (const float*)d_in[0];
  const float* na   = (const float*)d_in[1];
  const float* ea   = (const float*)d_in[2];
  const float* Wg   = (const float*)d_in[3];
  const float* ag   = (const float*)d_in[4];
  const float* wihe = (const float*)d_in[5];
  const float* whhe = (const float*)d_in[6];
  const float* bihe = (const float*)d_in[7];
  const float* bhhe = (const float*)d_in[8];
  const float* wihn = (const float*)d_in[9];
  const float* whhn = (const float*)d_in[10];
  const float* bihn = (const float*)d_in[11];
  const float* bhhn = (const float*)d_in[12];
  float* out = (float*)d_out;
  float* ws  = (float*)d_ws;

  const size_t SZ = (size_t)NN * HH;
  const size_t need8 = (24 * SZ + 16 * NN + 4160 + 64) * 4 + (size_t)NN * HH * 2;
  const int KS = (ws_size >= need8) ? 8 : 4;

  float* SpP = ws;
  float* TfP = ws + (size_t)KS * SZ;
  float* TpP = ws + (size_t)2 * KS * SZ;
  float* Sp = SpP;
  float* Sm = SpP + SZ;
  float* HP = TfP;
  float* HM = TfP + SZ;
  float* U  = TfP + 2 * SZ;
  float* ES = TfP + 3 * SZ;
  float* Tp = TpP;
  float* Tm = TpP + SZ;
  float* EO = TpP + 2 * SZ;
  float* NO = TpP + 3 * SZ;
  float* small = ws + (size_t)3 * KS * SZ;
  float* cpP = small;
  float* cpF = cpP + (size_t)KS * NN;
  float* dn  = cpF + NN;
  float* de  = dn + NN;
  float* HbP = de + NN;
  float* Hb  = HbP + 4096;
  unsigned short* ht = (unsigned short*)(Hb + 64);

  k_diag<<<32, 256, 0, stream>>>(na, ea, dn, de);
  k_hbarP<<<64, 256, 0, stream>>>(h, HbP);
  k_hbarF<<<1, 64, 0, stream>>>(HbP, Hb);
  k_ht<<<NN / 64, 256, 0, stream>>>(h, ht);
  if (KS == 8) {
    k_stageA<8><<<dim3(NN / 64, 8), 256, 0, stream>>>(na, ea, ht, SpP, TfP, TpP, cpP);
    k_combine<8><<<(int)(SZ / 256), 256, 0, stream>>>(h, dn, de, Hb, SpP, TfP, TpP, cpP, cpF);
  } else {
    k_stageA<4><<<dim3(NN / 64, 4), 256, 0, stream>>>(na, ea, ht, SpP, TfP, TpP, cpP);
    k_combine<4><<<(int)(SZ / 256), 256, 0, stream>>>(h, dn, de, Hb, SpP, TfP, TpP, cpP, cpF);
  }
  k_mm64<<<NN / 16, 256, 0, stream>>>(Sp, Wg, HP);
  k_mm64<<<NN / 16, 256, 0, stream>>>(Sm, Wg, HM);
  k_gat<<<NN / 4, 256, 0, stream>>>(HP, HM, ag, Tp, Tm, cpF, U);
  k_mm64<<<NN / 16, 256, 0, stream>>>(U, Wg, ES);
  k_gru<128><<<NN / 8, 64, 0, stream>>>(Sp, Sm, wihe, whhe, bihe, bhhe, h, EO);
  k_gru<64><<<NN / 8, 64, 0, stream>>>(ES, nullptr, wihn, whhn, bihn, bhhn, h, NO);
  k_final<<<(int)(SZ / 256), 256, 0, stream>>>(dn, de, EO, NO, out);
}

// Round 5
// 264.136 us; speedup vs baseline: 1.6544x; 1.6544x over previous
//
#include <hip/hip_runtime.h>

#define NN 8192
#define HH 64
#define BK 32
constexpr float LALPHA = 0.2f;

typedef __attribute__((ext_vector_type(8))) short bf16x8;
typedef __attribute__((ext_vector_type(4))) float f32x4;

__device__ inline short f2bf(float f) {
  unsigned u = __builtin_bit_cast(unsigned, f);
  u += 0x7FFFu + ((u >> 16) & 1u);
  return (short)(u >> 16);
}

// async global->LDS, 16B per lane; LDS dest = uniform base + lane*16 (HW rule)
__device__ __forceinline__ void gl_lds16(const void* g, void* l) {
  __builtin_amdgcn_global_load_lds(
      (const __attribute__((address_space(1))) void*)g,
      (__attribute__((address_space(3))) void*)l, 16, 0, 0);
}

// ---------------------------------------------------------------- diag extract
__global__ __launch_bounds__(256) void k_diag(const float* __restrict__ na,
                                              const float* __restrict__ ea,
                                              float* __restrict__ dn,
                                              float* __restrict__ de) {
  int i = blockIdx.x * 256 + threadIdx.x;
  if (i < NN) {
    dn[i] = na[(size_t)i * NN + i];
    de[i] = ea[(size_t)i * NN + i];
  }
}

// ---------------------------------------------------------------- column sums of h
__global__ __launch_bounds__(256) void k_hbarP(const float* __restrict__ h,
                                               float* __restrict__ HbP) {
  int c = threadIdx.x & 63, rs = threadIdx.x >> 6;
  int r0 = blockIdx.x * 128;
  float s = 0.f;
  for (int r = rs; r < 128; r += 4) s += h[(size_t)(r0 + r) * HH + c];
  __shared__ float red[4][64];
  red[rs][c] = s;
  __syncthreads();
  if (rs == 0) HbP[blockIdx.x * 64 + c] = red[0][c] + red[1][c] + red[2][c] + red[3][c];
}

__global__ __launch_bounds__(64) void k_hbarF(const float* __restrict__ HbP,
                                              float* __restrict__ Hb) {
  int c = threadIdx.x;
  float s = 0.f;
  for (int b = 0; b < 64; ++b) s += HbP[b * 64 + c];
  Hb[c] = s;
}

// ---------------------------------------------------------------- h -> ht (transposed bf16 [64][NN])
__global__ __launch_bounds__(256) void k_ht(const float* __restrict__ h,
                                            unsigned short* __restrict__ ht) {
  __shared__ float tile[64][65];
  int j0 = blockIdx.x * 64;
  for (int l = threadIdx.x; l < 64 * 64; l += 256) {
    int r = l >> 6, c = l & 63;
    tile[r][c] = h[(size_t)(j0 + r) * HH + c];
  }
  __syncthreads();
  for (int l = threadIdx.x; l < 64 * 64; l += 256) {
    int c = l >> 6, r = l & 63;
    ht[(size_t)c * NN + j0 + r] = (unsigned short)f2bf(tile[r][c]);
  }
}

// ---------------------------------------------------------------- heavy masked matmuls via MFMA
// Staged pipeline: global_load_lds (contiguous 1KB/instr) -> LDS dbuf ->
// ds_read_b128 fragments (XOR-swizzled, conflict-free) -> convert -> MFMA.
// Counted vmcnt(5): previous tile complete, current tile stays in flight.
template <int KS>
__global__ __launch_bounds__(256, 4) void k_stageA(
    const float* __restrict__ na, const float* __restrict__ ea,
    const unsigned short* __restrict__ ht,
    float* __restrict__ SpP, float* __restrict__ TfP,
    float* __restrict__ TpP, float* __restrict__ cpP) {
  __align__(16) __shared__ float lsA[2][64 * BK];           // 2 x 8 KB
  __align__(16) __shared__ float lsE[2][64 * BK];           // 2 x 8 KB
  __align__(16) __shared__ unsigned short lsH[2][64 * BK];  // 2 x 4 KB
  const int lane  = threadIdx.x & 63;
  const int w     = threadIdx.x >> 6;
  const int row16 = lane & 15;
  const int kgrp  = lane >> 4;
  const int i0    = blockIdx.x * 64 + w * 16;
  const int kbeg  = blockIdx.y * (NN / KS);
  constexpr int NSTEP = NN / KS / BK;

  // staging source pointers, pre-swizzled so linear LDS dest => swizzled layout
  // na/ea: row = 8 slots of 16B, slot' = slot ^ (row&7)
  const float* gA[2];
  const float* gE[2];
  const unsigned short* gH[1];
#pragma unroll
  for (int m = 0; m < 2; ++m) {
    const int u = w * 128 + m * 64 + lane;  // 16B-unit index in tile
    const int row = u >> 3;
    const int s = (lane & 7) ^ (row & 7);
    gA[m] = na + (size_t)(blockIdx.x * 64 + row) * NN + kbeg + s * 4;
    gE[m] = ea + (size_t)(blockIdx.x * 64 + row) * NN + kbeg + s * 4;
  }
  {
    // ht: row = 4 slots of 16B, slot' = slot ^ (row&3)
    const int u = w * 64 + lane;
    const int row = u >> 2;
    const int s = (lane & 3) ^ (row & 3);
    gH[0] = ht + (size_t)row * NN + kbeg + s * 8;
  }

#define STAGE(b)                                                      \
  do {                                                                \
    _Pragma("unroll") for (int m = 0; m < 2; ++m)                     \
        gl_lds16(gA[m], &lsA[b][w * 512 + m * 256]);                  \
    _Pragma("unroll") for (int m = 0; m < 2; ++m)                     \
        gl_lds16(gE[m], &lsE[b][w * 512 + m * 256]);                  \
    gl_lds16(gH[0], &lsH[b][w * 512]);                                \
    _Pragma("unroll") for (int m = 0; m < 2; ++m) {                   \
      gA[m] += BK; gE[m] += BK;                                       \
    }                                                                 \
    gH[0] += BK;                                                      \
  } while (0)

  f32x4 accS[4] = {}, accF[4] = {}, accP[4] = {};
  float cnt = 0.f;

  STAGE(0);
  int cur = 0;
  for (int t = 0; t < NSTEP; ++t) {
    if (t + 1 < NSTEP) {
      STAGE(cur ^ 1);
      asm volatile("s_waitcnt vmcnt(5)" ::: "memory");  // prev tile landed
    } else {
      asm volatile("s_waitcnt vmcnt(0)" ::: "memory");
    }
    __builtin_amdgcn_sched_barrier(0);
    asm volatile("s_barrier" ::: "memory");

    {
      const int R = w * 16 + row16;
      const int sb = kgrp * 2;
      const int u0 = R * 8 + (sb ^ (row16 & 7));
      const int u1 = R * 8 + ((sb + 1) ^ (row16 & 7));
      const float4 A0 = *(const float4*)&lsA[cur][u0 * 4];
      const float4 A1 = *(const float4*)&lsA[cur][u1 * 4];
      const float4 E0 = *(const float4*)&lsE[cur][u0 * 4];
      const float4 E1 = *(const float4*)&lsE[cur][u1 * 4];
      const float av[8] = {A0.x, A0.y, A0.z, A0.w, A1.x, A1.y, A1.z, A1.w};
      const float ev[8] = {E0.x, E0.y, E0.z, E0.w, E1.x, E1.y, E1.z, E1.w};
      bf16x8 fS, fF, fP;
#pragma unroll
      for (int q = 0; q < 8; ++q) {
        fS[q] = (av[q] > 0.f) ? (short)0x3F80 : (short)0;
        fF[q] = f2bf(ev[q]);
        fP[q] = f2bf(fmaxf(ev[q], 0.f));
        cnt += (ev[q] > 0.f) ? 1.f : 0.f;
      }
#pragma unroll
      for (int c = 0; c < 4; ++c) {
        const int hr = c * 16 + row16;
        const bf16x8 fB =
            *(const bf16x8*)&lsH[cur][hr * 32 + ((kgrp ^ (row16 & 3)) * 8)];
        accS[c] = __builtin_amdgcn_mfma_f32_16x16x32_bf16(fS, fB, accS[c], 0, 0, 0);
        accF[c] = __builtin_amdgcn_mfma_f32_16x16x32_bf16(fF, fB, accF[c], 0, 0, 0);
        accP[c] = __builtin_amdgcn_mfma_f32_16x16x32_bf16(fP, fB, accP[c], 0, 0, 0);
      }
    }
    asm volatile("s_waitcnt lgkmcnt(0)" ::: "memory");
    __builtin_amdgcn_sched_barrier(0);
    asm volatile("s_barrier" ::: "memory");
    cur ^= 1;
  }
#undef STAGE

  cnt += __shfl_xor(cnt, 16);
  cnt += __shfl_xor(cnt, 32);
  if (lane < 16) cpP[blockIdx.y * NN + i0 + lane] = cnt;

  const size_t base = (size_t)blockIdx.y * ((size_t)NN * HH);
#pragma unroll
  for (int c = 0; c < 4; ++c) {
#pragma unroll
    for (int r = 0; r < 4; ++r) {
      const int row = i0 + kgrp * 4 + r;
      const int col = c * 16 + row16;
      const size_t idx = base + (size_t)row * HH + col;
      SpP[idx] = accS[c][r];
      TfP[idx] = accF[c][r];
      TpP[idx] = accP[c][r];
    }
  }
}

// ---------------------------------------------------------------- combine partials
template <int KS>
__global__ __launch_bounds__(256) void k_combine(
    const float* __restrict__ h, const float* __restrict__ dn,
    const float* __restrict__ de, const float* __restrict__ Hb,
    float* __restrict__ SpP, float* __restrict__ TfP,
    float* __restrict__ TpP, const float* __restrict__ cpP,
    float* __restrict__ cpF) {
  const int SZ = NN * HH;
  int idx = blockIdx.x * 256 + threadIdx.x;
  int i = idx >> 6, c = idx & 63;
  float hic = h[idx];
  float dni = dn[i], dei = de[i];
  float sp = 0.f, tf = 0.f, tp = 0.f;
#pragma unroll
  for (int s = 0; s < KS; ++s) {
    sp += SpP[(size_t)s * SZ + idx];
    tf += TfP[(size_t)s * SZ + idx];
    tp += TpP[(size_t)s * SZ + idx];
  }
  sp -= (dni > 0.f) ? hic : 0.f;
  tf -= dei * hic;
  tp -= fmaxf(dei, 0.f) * hic;
  SpP[idx] = sp;                       // Sp
  SpP[SZ + idx] = Hb[c] - hic - sp;    // Sm
  TpP[idx] = tp;                       // Tp
  TpP[SZ + idx] = tf - tp;             // Tm
  if (idx < NN) {
    float cntv = 0.f;
#pragma unroll
    for (int s = 0; s < KS; ++s) cntv += cpP[s * NN + idx];
    cntv -= (de[idx] > 0.f) ? 1.f : 0.f;
    cpF[idx] = cntv;
  }
}

// ---------------------------------------------------------------- [N,64] @ [64,64]
__global__ __launch_bounds__(256) void k_mm64(const float* __restrict__ X,
                                              const float* __restrict__ W,
                                              float* __restrict__ Y) {
  __shared__ float Ws[64][64];
  __shared__ float Xs[16][64];
  const int t = threadIdx.x;
  for (int l = t; l < 4096; l += 256) Ws[l >> 6][l & 63] = W[l];
  const int i0 = blockIdx.x * 16;
  for (int l = t; l < 1024; l += 256)
    Xs[l >> 6][l & 63] = X[(size_t)(i0 + (l >> 6)) * 64 + (l & 63)];
  __syncthreads();
  const int lane = t & 63, wid = t >> 6;
  float acc[4] = {0.f, 0.f, 0.f, 0.f};
  for (int k = 0; k < 64; ++k) {
    float wv = Ws[k][lane];
#pragma unroll
    for (int r = 0; r < 4; ++r) acc[r] += Xs[wid * 4 + r][k] * wv;
  }
#pragma unroll
  for (int r = 0; r < 4; ++r) Y[(size_t)(i0 + wid * 4 + r) * 64 + lane] = acc[r];
}

// ---------------------------------------------------------------- analytic GAT softmax
__global__ __launch_bounds__(256) void k_gat(
    const float* __restrict__ HP, const float* __restrict__ HM,
    const float* __restrict__ a, const float* __restrict__ Tp,
    const float* __restrict__ Tm, const float* __restrict__ cpF,
    float* __restrict__ U) {
  const int lane = threadIdx.x & 63;
  const int i = blockIdx.x * 4 + (threadIdx.x >> 6);
  const int idx = i * 64 + lane;
  float hp = HP[idx], hm = HM[idx];
  float a0 = a[lane], a1 = a[64 + lane];
  float ep = hp * a0 + hm * a1;
  float em = hm * a0 + hp * a1;
#pragma unroll
  for (int off = 32; off >= 1; off >>= 1) {
    ep += __shfl_xor(ep, off);
    em += __shfl_xor(em, off);
  }
  ep = ep > 0.f ? ep : LALPHA * ep;
  em = em > 0.f ? em : LALPHA * em;
  float cp = cpF[i];
  float cm = (float)(NN - 1) - cp;
  const float NEGI = -3.0e38f;
  float m = fmaxf(cp > 0.f ? ep : NEGI, cm > 0.f ? em : NEGI);
  float xp = (cp > 0.f) ? expf(ep - m) : 0.f;
  float xm = (cm > 0.f) ? expf(em - m) : 0.f;
  float denom = cp * xp + cm * xm;
  float inv = denom > 0.f ? 1.f / denom : 0.f;
  float wp = xp * inv, wm = xm * inv;
  U[idx] = wp * Tp[idx] + wm * Tm[idx];
}

// ---------------------------------------------------------------- GRU cell (r,z,n)
template <int XK>
__global__ __launch_bounds__(64) void k_gru(
    const float* __restrict__ x1, const float* __restrict__ x2,
    const float* __restrict__ wih, const float* __restrict__ whh,
    const float* __restrict__ bih, const float* __restrict__ bhh,
    const float* __restrict__ h, float* __restrict__ out) {
  const int c = threadIdx.x;
  const int i0 = blockIdx.x * 8;
  __shared__ float xs[8][XK];
  __shared__ float hs[8][64];
  for (int l = c; l < 8 * XK; l += 64) {
    int r = l / XK, k = l % XK;
    float v;
    if (XK == 128)
      v = (k < 64) ? x1[(size_t)(i0 + r) * 64 + k]
                   : x2[(size_t)(i0 + r) * 64 + (k - 64)];
    else
      v = x1[(size_t)(i0 + r) * 64 + k];
    xs[r][k] = v;
  }
  for (int l = c; l < 8 * 64; l += 64) {
    int r = l >> 6, k = l & 63;
    hs[r][k] = h[(size_t)(i0 + r) * 64 + k];
  }
  __syncthreads();
  float gr[8] = {}, gz[8] = {}, gn[8] = {};
  for (int k = 0; k < XK; ++k) {
    float wr = wih[(size_t)c * XK + k];
    float wz = wih[(size_t)(64 + c) * XK + k];
    float wn = wih[(size_t)(128 + c) * XK + k];
#pragma unroll
    for (int r = 0; r < 8; ++r) {
      float xv = xs[r][k];
      gr[r] += xv * wr; gz[r] += xv * wz; gn[r] += xv * wn;
    }
  }
  float hr[8] = {}, hz[8] = {}, hn[8] = {};
  for (int k = 0; k < 64; ++k) {
    float ur = whh[(size_t)c * 64 + k];
    float uz = whh[(size_t)(64 + c) * 64 + k];
    float un = whh[(size_t)(128 + c) * 64 + k];
#pragma unroll
    for (int r = 0; r < 8; ++r) {
      float hv = hs[r][k];
      hr[r] += hv * ur; hz[r] += hv * uz; hn[r] += hv * un;
    }
  }
  float br = bih[c], bz = bih[64 + c], bn = bih[128 + c];
  float dr = bhh[c], dz = bhh[64 + c], dnb = bhh[128 + c];
#pragma unroll
  for (int r = 0; r < 8; ++r) {
    float rg = 1.f / (1.f + expf(-(gr[r] + br + hr[r] + dr)));
    float zg = 1.f / (1.f + expf(-(gz[r] + bz + hz[r] + dz)));
    float ng = tanhf(gn[r] + bn + rg * (hn[r] + dnb));
    out[(size_t)(i0 + r) * 64 + c] = (1.f - zg) * ng + zg * hs[r][c];
  }
}

// ---------------------------------------------------------------- final combine
__global__ __launch_bounds__(256) void k_final(const float* __restrict__ dn,
                                               const float* __restrict__ de,
                                               const float* __restrict__ EO,
                                               const float* __restrict__ NO,
                                               float* __restrict__ out) {
  int idx = blockIdx.x * 256 + threadIdx.x;
  int i = idx >> 6;
  out[idx] = de[i] * EO[idx] + dn[i] * NO[idx];
}

extern "C" void kernel_launch(void* const* d_in, const int* in_sizes, int n_in,
                              void* d_out, int out_size, void* d_ws, size_t ws_size,
                              hipStream_t stream) {
  const float* h    = (const float*)d_in[0];
  const float* na   = (const float*)d_in[1];
  const float* ea   = (const float*)d_in[2];
  const float* Wg   = (const float*)d_in[3];
  const float* ag   = (const float*)d_in[4];
  const float* wihe = (const float*)d_in[5];
  const float* whhe = (const float*)d_in[6];
  const float* bihe = (const float*)d_in[7];
  const float* bhhe = (const float*)d_in[8];
  const float* wihn = (const float*)d_in[9];
  const float* whhn = (const float*)d_in[10];
  const float* bihn = (const float*)d_in[11];
  const float* bhhn = (const float*)d_in[12];
  float* out = (float*)d_out;
  float* ws  = (float*)d_ws;

  const size_t SZ = (size_t)NN * HH;
  const size_t need8 = (24 * SZ + 16 * NN + 4160 + 64) * 4 + (size_t)NN * HH * 2;
  const int KS = (ws_size >= need8) ? 8 : 4;

  float* SpP = ws;
  float* TfP = ws + (size_t)KS * SZ;
  float* TpP = ws + (size_t)2 * KS * SZ;
  float* Sp = SpP;
  float* Sm = SpP + SZ;
  float* HP = TfP;
  float* HM = TfP + SZ;
  float* U  = TfP + 2 * SZ;
  float* ES = TfP + 3 * SZ;
  float* Tp = TpP;
  float* Tm = TpP + SZ;
  float* EO = TpP + 2 * SZ;
  float* NO = TpP + 3 * SZ;
  float* small = ws + (size_t)3 * KS * SZ;
  float* cpP = small;
  float* cpF = cpP + (size_t)KS * NN;
  float* dn  = cpF + NN;
  float* de  = dn + NN;
  float* HbP = de + NN;
  float* Hb  = HbP + 4096;
  unsigned short* ht = (unsigned short*)(Hb + 64);

  k_diag<<<32, 256, 0, stream>>>(na, ea, dn, de);
  k_hbarP<<<64, 256, 0, stream>>>(h, HbP);
  k_hbarF<<<1, 64, 0, stream>>>(HbP, Hb);
  k_ht<<<NN / 64, 256, 0, stream>>>(h, ht);
  if (KS == 8) {
    k_stageA<8><<<dim3(NN / 64, 8), 256, 0, stream>>>(na, ea, ht, SpP, TfP, TpP, cpP);
    k_combine<8><<<(int)(SZ / 256), 256, 0, stream>>>(h, dn, de, Hb, SpP, TfP, TpP, cpP, cpF);
  } else {
    k_stageA<4><<<dim3(NN / 64, 4), 256, 0, stream>>>(na, ea, ht, SpP, TfP, TpP, cpP);
    k_combine<4><<<(int)(SZ / 256), 256, 0, stream>>>(h, dn, de, Hb, SpP, TfP, TpP, cpP, cpF);
  }
  k_mm64<<<NN / 16, 256, 0, stream>>>(Sp, Wg, HP);
  k_mm64<<<NN / 16, 256, 0, stream>>>(Sm, Wg, HM);
  k_gat<<<NN / 4, 256, 0, stream>>>(HP, HM, ag, Tp, Tm, cpF, U);
  k_mm64<<<NN / 16, 256, 0, stream>>>(U, Wg, ES);
  k_gru<128><<<NN / 8, 64, 0, stream>>>(Sp, Sm, wihe, whhe, bihe, bhhe, h, EO);
  k_gru<64><<<NN / 8, 64, 0, stream>>>(ES, nullptr, wihn, whhn, bihn, bhhn, h, NO);
  k_final<<<(int)(SZ / 256), 256, 0, stream>>>(dn, de, EO, NO, out);
}